// Round 15
// baseline (141.358 us; speedup 1.0000x reference)
//
#include <hip/hip_runtime.h>

// Problem constants
constexpr int B_ = 32, C_ = 64, H_ = 64, W_ = 64, K_ = 1024;
constexpr int NTOT = B_ * C_ * H_ * W_;          // 8388608 elements of input1/quantized
constexpr int NSP  = B_ * H_ * W_;               // 131072 spatial positions
// d_out float offsets: [0]=loss, [1..32]=input2_KL, [33..33+NTOT)=quantized(BCHW),
// [OFF_ENC .. OFF_ENC+NSP*K)=encodings
constexpr int OFF_Q   = 33;
constexpr int OFF_ENC = OFF_Q + NTOT;            // 8388641 (byte 33554564 == 4 mod 64)
constexpr long long ENC_ELEMS = (long long)NSP * K_;   // 134217728 (2^27)
// Zeroed interior: elements [ENC_HEAD, ENC_ELEMS-1) rel. OFF_ENC (64B-aligned
// start). Head cols 0..14 of row 0 and the final element are patched in K2.
constexpr int ENC_HEAD = 15;
constexpr int ENC_NQ   = (int)((ENC_ELEMS - ENC_HEAD - 1) / 4);  // 33554428 quads

constexpr int ZB   = 4096;                       // zero-fill blocks
constexpr int QPB  = 8192;                       // quads per zero block = 128 KB
// ZB*QPB = 33554432 = ENC_NQ + 4: last block trims 4 quads.
constexpr int MAIN_BLOCKS = NSP / 64;            // 2048
constexpr int K1_BLOCKS   = ZB + MAIN_BLOCKS;    // 6144

typedef float v4f __attribute__((ext_vector_type(4)));

// K1. Blocks [0, ZB): lean zero-fill in the rocclr fillBufferAligned shape —
// 32 fully-unrolled 16B stores of a CONSTANT register quad (no loads, no
// barriers, no waitcnt in the body -> stores pipeline to the HW limit; one WG
// amortizes launch setup over 128 KB). Blocks [ZB, K1_BLOCKS): quantized+loss
// (R14 body), dispatched last so the latency-bound gather overlaps the fill's
// drain tail (R14's proven win) instead of serializing in front.
__global__ __launch_bounds__(256) void vq_k1(const float* __restrict__ input1,
                                             const int*   __restrict__ x_tilde,
                                             const float* __restrict__ weight,
                                             float* __restrict__ out,  // d_out base
                                             float* __restrict__ ws) { // d_ws partials
    const int bid = blockIdx.x;
    const int tid = threadIdx.x;
    if (bid < ZB) {
        // ---- pure zero fill: 128 KB contiguous per block ----
        float* p = out + OFF_ENC + ENC_HEAD + bid * (QPB * 4) + (tid << 2);
        const v4f z = {0.f, 0.f, 0.f, 0.f};
        if (bid != ZB - 1) {
            #pragma unroll
            for (int i = 0; i < 32; ++i)
                *reinterpret_cast<v4f*>(p + i * 1024) = z;   // stride 4 KB/iter
        } else {
            constexpr int LAST_NQ = ENC_NQ - (ZB - 1) * QPB; // 8188 quads
            #pragma unroll
            for (int i = 0; i < 32; ++i)
                if (i * 256 + tid < LAST_NQ)
                    *reinterpret_cast<v4f*>(p + i * 1024) = z;
        }
        return;
    }

    // ---- quantized + loss path (transposed gather, 4-way channel split) ----
    const int mq  = bid - ZB;                        // 0..MAIN_BLOCKS-1
    const int n   = mq * 64 + (tid & 63);            // [0, NSP)
    const int cq  = tid >> 6;                        // 0..3 -> channels 16cq..16cq+15
    const int b   = n >> 12;                         // H*W = 4096
    const int hw  = n & 4095;
    const int t   = x_tilde[n];
    const float* __restrict__ wrow = weight + (t << 6) + (cq << 4);
    const float* __restrict__ xin  = input1 + (b << 18) + (cq << 16) + hw;
    float* __restrict__ qout = out + OFF_Q + (b << 18) + (cq << 16) + hw;

    const float4 w0 = *reinterpret_cast<const float4*>(wrow);
    const float4 w1 = *reinterpret_cast<const float4*>(wrow + 4);
    const float4 w2 = *reinterpret_cast<const float4*>(wrow + 8);
    const float4 w3 = *reinterpret_cast<const float4*>(wrow + 12);
    const float wv[16] = {w0.x, w0.y, w0.z, w0.w, w1.x, w1.y, w1.z, w1.w,
                          w2.x, w2.y, w2.z, w2.w, w3.x, w3.y, w3.z, w3.w};
    float local = 0.f;
    #pragma unroll
    for (int j = 0; j < 16; ++j) {
        const float x = xin[j << 12];
        const float d = wv[j] - x;
        qout[j << 12] = x + d;       // straight-through: x + (q - x)
        local += d * d;
    }

    // wave64 reduce + one plain store per block (overwrites; no zeroing needed)
    for (int o = 32; o > 0; o >>= 1) local += __shfl_down(local, o);
    __shared__ float sm[4];
    const int lane = tid & 63, wid = tid >> 6;
    if (lane == 0) sm[wid] = local;
    __syncthreads();
    if (tid == 0) {
        ws[mq] = sm[0] + sm[1] + sm[2] + sm[3];
    }
}

// K2. Blocks [0, 512): scatter the NSP ones into the zeroed region (ordered
// after K1 by stream order). Block 512: reduce partials -> loss, KL
// passthrough, and patch the 16 edge elements the aligned fill skipped.
__global__ __launch_bounds__(256) void vq_k2(const int* __restrict__ x_tilde,
                                             const float* __restrict__ ws,
                                             const float* __restrict__ kl,
                                             float* __restrict__ out) {
    const int bid = blockIdx.x;
    const int tid = threadIdx.x;
    if (bid < NSP / 256) {
        const int n = (bid << 8) + tid;
        const int t = x_tilde[n];
        out[OFF_ENC + (n << 10) + t] = 1.0f;   // head/tail overlaps are same-value
        return;
    }
    float local = 0.f;
    #pragma unroll
    for (int k = 0; k < 8; ++k) local += ws[tid + (k << 8)];
    for (int o = 32; o > 0; o >>= 1) local += __shfl_down(local, o);
    __shared__ float sm[4];
    if ((tid & 63) == 0) sm[tid >> 6] = local;
    __syncthreads();
    if (tid == 0) out[0] = 1.25f * (sm[0] + sm[1] + sm[2] + sm[3]) / (float)NTOT;
    if (tid >= 64 && tid < 96) out[1 + tid - 64] = kl[tid - 64];
    if (tid == 96) {
        const int t0 = x_tilde[0];
        #pragma unroll
        for (int j = 0; j < ENC_HEAD; ++j)
            out[OFF_ENC + j] = (t0 == j) ? 1.f : 0.f;      // row 0, cols 0..14
        const int tl = x_tilde[NSP - 1];
        out[OFF_ENC + (int)ENC_ELEMS - 1] = (tl == 1023) ? 1.f : 0.f;
    }
}

extern "C" void kernel_launch(void* const* d_in, const int* in_sizes, int n_in,
                              void* d_out, int out_size, void* d_ws, size_t ws_size,
                              hipStream_t stream) {
    const float* input1 = (const float*)d_in[0];
    const float* kl     = (const float*)d_in[1];
    const float* weight = (const float*)d_in[2];
    const int*   x_til  = (const int*)d_in[3];
    float* out = (float*)d_out;
    float* ws  = (float*)d_ws;

    vq_k1<<<K1_BLOCKS, 256, 0, stream>>>(input1, x_til, weight, out, ws);
    vq_k2<<<NSP / 256 + 1, 256, 0, stream>>>(x_til, ws, kl, out);
}

// Round 16
// 106.521 us; speedup vs baseline: 1.3270x; 1.3270x over previous
//
#include <hip/hip_runtime.h>

// Problem constants
constexpr int B_ = 32, C_ = 64, H_ = 64, W_ = 64, K_ = 1024;
constexpr int NTOT = B_ * C_ * H_ * W_;          // 8388608 elements of input1/quantized
constexpr int NSP  = B_ * H_ * W_;               // 131072 spatial positions
// d_out float offsets: [0]=loss, [1..32]=input2_KL, [33..33+NTOT)=quantized(BCHW),
// [OFF_ENC .. OFF_ENC+NSP*K)=encodings
constexpr int OFF_Q   = 33;
constexpr int OFF_ENC = OFF_Q + NTOT;            // 8388641 (byte 33554564 == 4 mod 64)
constexpr long long ENC_ELEMS = (long long)NSP * K_;   // 134217728 (2^27)
// (OFF_ENC + 15)*4 == 0 mod 64: fill starts 64B-LINE-aligned.
// Head (row 0, cols 0..14) and tail (last row, col 1023) patched in vq_fin.
constexpr int ENC_HEAD = 15;
constexpr int ENC_NQ = (int)((ENC_ELEMS - ENC_HEAD - 1) / 4);   // 33554428 quads
constexpr int ENC_BLOCKS = (ENC_NQ + 255) / 256;                // 131072 blocks

constexpr int MAIN_BLOCKS  = NSP / 64;                          // 2048 blocks
constexpr int TOTAL_BLOCKS = ENC_BLOCKS + MAIN_BLOCKS;          // 133120

typedef float v4f __attribute__((ext_vector_type(4)));

// Fused kernel, ENC FIRST / MAIN LAST (R14 structure, best = 122.5 us).
// Delta vs R14: (a) enc stores are NONTEMPORAL (no-allocate / evict-first in
// L2) — untested in the one-shot shape; a pure 537 MB write stream gains if
// dirty-line allocation churn was throttling it; (b) main path uses per-wave
// partials (no LDS, no __syncthreads) -> zero sync in the hot kernel.
__global__ __launch_bounds__(256) void vq_fused(const float* __restrict__ input1,
                                                const int*   __restrict__ x_tilde,
                                                const float* __restrict__ weight,
                                                float* __restrict__ out,  // d_out base
                                                float* __restrict__ ws) { // d_ws partials
    const int bid = blockIdx.x;
    if (bid < ENC_BLOCKS) {
        // ---- encodings fill path (one-shot: one 16B NT store per thread) ----
        const int b  = bid;
        const int qi = b * 256 + threadIdx.x;
        if (qi >= ENC_NQ) return;             // 4 idle threads in the last block
        const int t0 = x_tilde[b];
        const int t1 = x_tilde[(b + 1 < NSP) ? b + 1 : NSP - 1];
        const int col0 = ENC_HEAD + (threadIdx.x << 2);        // 15..1035 rel. row b
        v4f v;
        #pragma unroll
        for (int j = 0; j < 4; ++j) {
            const int col = col0 + j;
            ((float*)&v)[j] = (col < 1024) ? ((t0 == col) ? 1.f : 0.f)
                                           : ((t1 == col - 1024) ? 1.f : 0.f);
        }
        __builtin_nontemporal_store(v,
            reinterpret_cast<v4f*>(out + OFF_ENC + ENC_HEAD + (qi << 2)));
        return;
    }

    // ---- quantized + loss path (transposed gather, 4-way channel split) ----
    const int mq  = bid - ENC_BLOCKS;                // 0..MAIN_BLOCKS-1
    const int tid = threadIdx.x;
    const int n   = mq * 64 + (tid & 63);            // [0, NSP)
    const int cq  = tid >> 6;                        // 0..3 -> channels 16cq..16cq+15
    const int b   = n >> 12;                         // H*W = 4096
    const int hw  = n & 4095;
    const int t   = x_tilde[n];
    const float* __restrict__ wrow = weight + (t << 6) + (cq << 4);
    const float* __restrict__ xin  = input1 + (b << 18) + (cq << 16) + hw;
    float* __restrict__ qout = out + OFF_Q + (b << 18) + (cq << 16) + hw;

    const float4 w0 = *reinterpret_cast<const float4*>(wrow);
    const float4 w1 = *reinterpret_cast<const float4*>(wrow + 4);
    const float4 w2 = *reinterpret_cast<const float4*>(wrow + 8);
    const float4 w3 = *reinterpret_cast<const float4*>(wrow + 12);
    const float wv[16] = {w0.x, w0.y, w0.z, w0.w, w1.x, w1.y, w1.z, w1.w,
                          w2.x, w2.y, w2.z, w2.w, w3.x, w3.y, w3.z, w3.w};
    float local = 0.f;
    #pragma unroll
    for (int j = 0; j < 16; ++j) {
        const float x = xin[j << 12];
        const float d = wv[j] - x;
        qout[j << 12] = x + d;       // straight-through: x + (q - x)
        local += d * d;
    }

    // per-wave reduce; one plain store per wave -> ws[4*mq + wid]; no barrier
    for (int o = 32; o > 0; o >>= 1) local += __shfl_down(local, o);
    if ((tid & 63) == 0) {
        ws[(mq << 2) | (tid >> 6)] = local;
    }
}

// Finalize: reduce 8192 per-wave partials -> loss, input2_KL passthrough, and
// the 16 edge elements the line-aligned fill skipped.
__global__ __launch_bounds__(256) void vq_fin(const int* __restrict__ x_tilde,
                                              const float* __restrict__ ws,
                                              const float* __restrict__ kl,
                                              float* __restrict__ out) {
    const int tid = threadIdx.x;
    float local = 0.f;
    #pragma unroll
    for (int k = 0; k < 32; ++k) local += ws[tid + (k << 8)];
    for (int o = 32; o > 0; o >>= 1) local += __shfl_down(local, o);
    __shared__ float sm[4];
    if ((tid & 63) == 0) sm[tid >> 6] = local;
    __syncthreads();
    if (tid == 0) out[0] = 1.25f * (sm[0] + sm[1] + sm[2] + sm[3]) / (float)NTOT;
    if (tid >= 64 && tid < 96) out[1 + tid - 64] = kl[tid - 64];
    if (tid == 96) {
        const int t0 = x_tilde[0];
        #pragma unroll
        for (int j = 0; j < ENC_HEAD; ++j)
            out[OFF_ENC + j] = (t0 == j) ? 1.f : 0.f;      // row 0, cols 0..14
        const int tl = x_tilde[NSP - 1];
        out[OFF_ENC + (int)ENC_ELEMS - 1] = (tl == 1023) ? 1.f : 0.f;
    }
}

extern "C" void kernel_launch(void* const* d_in, const int* in_sizes, int n_in,
                              void* d_out, int out_size, void* d_ws, size_t ws_size,
                              hipStream_t stream) {
    const float* input1 = (const float*)d_in[0];
    const float* kl     = (const float*)d_in[1];
    const float* weight = (const float*)d_in[2];
    const int*   x_til  = (const int*)d_in[3];
    float* out = (float*)d_out;
    float* ws  = (float*)d_ws;

    vq_fused<<<TOTAL_BLOCKS, 256, 0, stream>>>(input1, x_til, weight, out, ws);
    vq_fin<<<1, 256, 0, stream>>>(x_til, ws, kl, out);
}